// Round 8
// baseline (371.815 us; speedup 1.0000x reference)
//
#include <hip/hip_runtime.h>
#include <stdint.h>

typedef short bf16x8 __attribute__((ext_vector_type(8)));
typedef float f32x4 __attribute__((ext_vector_type(4)));

#define M_ROWS 8192
#define N_OUT  4096
#define K_DIM  4096
#define NW     16777216.0   // number of weights

// ---------------- async global->LDS (16B per lane) ----------------
__device__ __forceinline__ void gload16(const void* g, void* l) {
    __builtin_amdgcn_global_load_lds((const __attribute__((address_space(1))) void*)g,
                                     (__attribute__((address_space(3))) void*)l,
                                     16, 0, 0);
}

// RNE f32 -> bf16 bits
__device__ __forceinline__ unsigned short f2bf(float f) {
    unsigned u = __float_as_uint(f);
    unsigned r = 0x7FFFu + ((u >> 16) & 1u);
    return (unsigned short)((u + r) >> 16);
}

// ---------------- gamma = sum |w| (double accumulation) ----------------
__global__ __launch_bounds__(256) void k_gamma(const float* __restrict__ w,
                                               double* __restrict__ sum) {
    const int n4 = (K_DIM * N_OUT) / 4;
    int idx = blockIdx.x * blockDim.x + threadIdx.x;
    int stride = gridDim.x * blockDim.x;
    const float4* w4 = (const float4*)w;
    double local = 0.0;
    for (int i = idx; i < n4; i += stride) {
        float4 v = w4[i];
        local += (double)fabsf(v.x) + (double)fabsf(v.y) +
                 (double)fabsf(v.z) + (double)fabsf(v.w);
    }
    __shared__ double sm[256];
    sm[threadIdx.x] = local;
    __syncthreads();
    for (int s = 128; s > 0; s >>= 1) {
        if (threadIdx.x < s) sm[threadIdx.x] += sm[threadIdx.x + s];
        __syncthreads();
    }
    if (threadIdx.x == 0) atomicAdd(sum, sm[0]);
}

// ---------------- quantize W -> ternary bf16 + bin counts ----------------
__global__ __launch_bounds__(256) void k_quant(const float* __restrict__ w,
                                               const double* __restrict__ sum,
                                               unsigned short* __restrict__ wq,
                                               unsigned int* __restrict__ counts,
                                               int do_store) {
    const float gamma = (float)(*sum / NW);
    const float denom = gamma + 1e-8f;
    const int n4 = (K_DIM * N_OUT) / 4;
    int idx = blockIdx.x * blockDim.x + threadIdx.x;
    int stride = gridDim.x * blockDim.x;
    const float4* w4 = (const float4*)w;
    unsigned cm = 0, cp = 0;
    for (int i = idx; i < n4; i += stride) {
        float4 v = w4[i];
        float q0 = fminf(1.f, fmaxf(-1.f, rintf(v.x / denom)));
        float q1 = fminf(1.f, fmaxf(-1.f, rintf(v.y / denom)));
        float q2 = fminf(1.f, fmaxf(-1.f, rintf(v.z / denom)));
        float q3 = fminf(1.f, fmaxf(-1.f, rintf(v.w / denom)));
        cm += (q0 < -0.5f) + (q1 < -0.5f) + (q2 < -0.5f) + (q3 < -0.5f);
        cp += (q0 >  0.5f) + (q1 >  0.5f) + (q2 >  0.5f) + (q3 >  0.5f);
        if (do_store) {
            unsigned b0 = (q0 < -0.5f) ? 0xBF80u : (q0 > 0.5f ? 0x3F80u : 0u);
            unsigned b1 = (q1 < -0.5f) ? 0xBF80u : (q1 > 0.5f ? 0x3F80u : 0u);
            unsigned b2 = (q2 < -0.5f) ? 0xBF80u : (q2 > 0.5f ? 0x3F80u : 0u);
            unsigned b3 = (q3 < -0.5f) ? 0xBF80u : (q3 > 0.5f ? 0x3F80u : 0u);
            uint2 pk;
            pk.x = b0 | (b1 << 16);
            pk.y = b2 | (b3 << 16);
            ((uint2*)wq)[i] = pk;
        }
    }
    __shared__ unsigned smc[512];
    smc[threadIdx.x] = cm;
    smc[256 + threadIdx.x] = cp;
    __syncthreads();
    for (int s = 128; s > 0; s >>= 1) {
        if (threadIdx.x < s) {
            smc[threadIdx.x] += smc[threadIdx.x + s];
            smc[256 + threadIdx.x] += smc[256 + threadIdx.x + s];
        }
        __syncthreads();
    }
    if (threadIdx.x == 0) {
        atomicAdd(&counts[0], smc[0]);
        atomicAdd(&counts[1], smc[256]);
    }
}

// ---------------- x f32 -> bf16 ----------------
__global__ __launch_bounds__(256) void k_cvt(const float* __restrict__ x,
                                             unsigned short* __restrict__ xb) {
    const int n4 = (M_ROWS * K_DIM) / 4;
    int idx = blockIdx.x * blockDim.x + threadIdx.x;
    int stride = gridDim.x * blockDim.x;
    const float4* x4 = (const float4*)x;
    for (int i = idx; i < n4; i += stride) {
        float4 v = x4[i];
        uint2 pk;
        pk.x = (unsigned)f2bf(v.x) | ((unsigned)f2bf(v.y) << 16);
        pk.y = (unsigned)f2bf(v.z) | ((unsigned)f2bf(v.w) << 16);
        ((uint2*)xb)[i] = pk;
    }
}

// ---------------- entropy + t_current ----------------
__global__ void k_fin(const unsigned int* __restrict__ counts,
                      float* __restrict__ outs) {
    double n = NW;
    double c1 = (double)counts[0];
    double c2 = (double)counts[1];
    double c0 = n - c1 - c2;
    double H = 0.0;
    if (c1 > 0.0) { double p = c1 / n; H -= p * log2(p); }
    if (c0 > 0.0) { double p = c0 / n; H -= p * log2(p); }
    if (c2 > 0.0) { double p = c2 / n; H -= p * log2(p); }
    float Hf = (float)H;
    float heat = 100.0f * fmaxf(Hf, 0.0f);
    outs[0] = -10.0f + (50.0f + heat) * 0.5f;
    outs[1] = Hf;
}

// ========== 256x256 bf16 MFMA GEMM, pipelined 4-phase per K-tile ==========
// C[M,N] = A[M,K] * B[N,K]^T. 512 threads = 8 waves (2M x 4N), per-wave 128x64.
// LDS 128KB: buf[2] x {A0,A1,B0,B1} halves (16KB each), fragment-major layout
// (off = (ks*8+sub16)*1024 + lane*16) -> ds_read_b128 contiguous, 0 conflicts
// (measured R5). Staging indices/gates identical to R7 (race-verified).
//
// R8 change: software-pipelined reads + COMPILER-managed counted lgkm waits.
// Each phase's reads are issued one MFMA cluster ahead of their consumer; no
// interior lgkmcnt(0)/sched_barrier (R5-R7's forced full drains serialized
// read-burst vs MFMA and idled the matrix pipe -> MfmaUtil stuck at 40%).
// Per tau:
//   issue A(m0,k0)+B(k0) [8]; stage A0(t+1); issue A(m0,k1)+B(k1) [8]
//   MFMA ph0 (m0,k0)
//   issue A(m1,k0) [4];  stage A1(t+1)
//   MFMA ph1 (m0,k1)
//   issue A(m1,k1) [4]
//   lgkmcnt(8) + mid barrier   (8 newest outstanding = the A(m1,*) reads ->
//                               all B reads landed -> B halves of buf[t&1] dead)
//   stage B0,B1(t+2)           (write buf[t&1] B halves - legal only here)
//   MFMA ph2 (m1,k0); MFMA ph3 (m1,k1)
//   lgkmcnt(0); vmcnt(4) [vmcnt(0) at t>=62]; boundary barrier
// vmcnt(4) at the gate: in-flight FIFO = [A0(t+1)x2, A1(t+1)x2, B(t+2)x4];
// waits oldest 4 -> A(t+1) landed; B(t+1) (older, from t-1) landed; B(t+2) fly.
// sched_barrier(0) only hugs the two s_barriers (rule #18), interiors free.

__device__ __forceinline__ void stage_half(const unsigned short* __restrict__ A,
                                           const unsigned short* __restrict__ B,
                                           char* lds, int H, int tm, int tn,
                                           int tid) {
    const int kt = H >> 2;
    const int q  = H & 3;                      // 0=A0 1=A1 2=B0 3=B1
    const unsigned short* src = (q & 2) ? B : A;
    const int rb = ((q & 2) ? tn : tm) * 256 + (q & 1) * 128;
    const int row = rb + ((tid >> 6) << 4) + (tid & 15);
    const unsigned short* g0 = src + (size_t)row * K_DIM + kt * 64 + ((tid >> 4) & 3) * 8;
    char* d = lds + ((size_t)(kt & 1) << 16) + (q << 14) + tid * 16;
    gload16(g0, d);              // ks=0: cols [khi*8, +8)
    gload16(g0 + 32, d + 8192);  // ks=1: cols [32+khi*8, +8)
}

// 16 MFMAs: one m-half x full n at one K-half; compiler inserts counted lgkm wait
#define MFMA_PH(MH, AF, BF)                                                    \
    __builtin_amdgcn_s_setprio(1);                                             \
    _Pragma("unroll") for (int mm = 0; mm < 4; ++mm)                           \
    _Pragma("unroll") for (int nn = 0; nn < 4; ++nn)                           \
        acc[(MH)*4 + mm][nn] = __builtin_amdgcn_mfma_f32_16x16x32_bf16(        \
            AF[mm], BF[nn], acc[(MH)*4 + mm][nn], 0, 0, 0);                    \
    __builtin_amdgcn_s_setprio(0);

__global__ __launch_bounds__(512, 2) void k_gemm2(const unsigned short* __restrict__ A,
                                                  const unsigned short* __restrict__ B,
                                                  float* __restrict__ C) {
    extern __shared__ char smem[];
    const int tid  = threadIdx.x;
    const int lane = tid & 63;
    const int wid  = tid >> 6;
    const int wr   = wid >> 2;        // 0..1  (M)
    const int wc   = wid & 3;         // 0..3  (N)
    const int fr   = lane & 15;
    const int khi  = lane >> 4;       // 0..3

    // XCD-aware swizzle (nwg=512 divisible by 8 -> bijective simple form).
    const int lin = blockIdx.x;
    const int s   = (lin & 7) * 64 + (lin >> 3);
    const int tm  = s & 31;           // 0..31 (M tiles)
    const int tn  = s >> 5;           // 0..15 (N tiles)

    f32x4 acc[8][4] = {};

    // prologue: tile0 all halves + B0,B1 of tile1; drain; publish
    stage_half(A, B, smem, 0, tm, tn, tid);
    stage_half(A, B, smem, 1, tm, tn, tid);
    stage_half(A, B, smem, 2, tm, tn, tid);
    stage_half(A, B, smem, 3, tm, tn, tid);
    stage_half(A, B, smem, 6, tm, tn, tid);
    stage_half(A, B, smem, 7, tm, tn, tid);
    asm volatile("s_waitcnt vmcnt(0)" ::: "memory");
    __builtin_amdgcn_s_barrier();

    bf16x8 afr0[4], afr1[4], bk0[4], bk1[4];
    const int bsel = (wc & 1) * 4;    // fragment group within B-half

    for (int tau = 0; tau < 64; ++tau) {
        const char* aptr = smem + ((size_t)(tau & 1) << 16) + ((size_t)wr << 14) + lane * 16;
        const char* bptr = smem + ((size_t)(tau & 1) << 16) + 32768 + ((size_t)(wc >> 1) << 14)
                         + bsel * 1024 + lane * 16;
        const int g = tau * 4;

        // issue ph0 reads: A(m0,k0) + B(k0)
#pragma unroll
        for (int mm = 0; mm < 4; ++mm)
            afr0[mm] = *(const bf16x8*)(aptr + (0 * 8 + mm) * 1024);
#pragma unroll
        for (int nn = 0; nn < 4; ++nn)
            bk0[nn] = *(const bf16x8*)(bptr + (0 * 8 + nn) * 1024);
        if (g + 4 < 256) stage_half(A, B, smem, g + 4, tm, tn, tid);
        // issue ph1 reads ahead: A(m0,k1) + B(k1)
#pragma unroll
        for (int mm = 0; mm < 4; ++mm)
            afr1[mm] = *(const bf16x8*)(aptr + (1 * 8 + mm) * 1024);
#pragma unroll
        for (int nn = 0; nn < 4; ++nn)
            bk1[nn] = *(const bf16x8*)(bptr + (1 * 8 + nn) * 1024);

        MFMA_PH(0, afr0, bk0)                 // ph0 (m0,k0)

        // issue ph2 reads ahead: A(m1,k0) (afr0 consumed by ph0 in program order)
#pragma unroll
        for (int mm = 0; mm < 4; ++mm)
            afr0[mm] = *(const bf16x8*)(aptr + (0 * 8 + 4 + mm) * 1024);
        if (g + 5 < 256) stage_half(A, B, smem, g + 5, tm, tn, tid);

        MFMA_PH(0, afr1, bk1)                 // ph1 (m0,k1)

        // issue ph3 reads ahead: A(m1,k1)
#pragma unroll
        for (int mm = 0; mm < 4; ++mm)
            afr1[mm] = *(const bf16x8*)(aptr + (1 * 8 + 4 + mm) * 1024);

        // mid fence: 8 newest outstanding lgkm = the A(m1,*) reads just issued
        // -> all B reads of buf[tau&1] landed; B halves safe to overwrite
        asm volatile("s_waitcnt lgkmcnt(8)" ::: "memory");
        __builtin_amdgcn_sched_barrier(0);
        __builtin_amdgcn_s_barrier();
        __builtin_amdgcn_sched_barrier(0);
        if (g + 10 < 256) stage_half(A, B, smem, g + 10, tm, tn, tid);
        if (g + 11 < 256) stage_half(A, B, smem, g + 11, tm, tn, tid);

        MFMA_PH(1, afr0, bk0)                 // ph2 (m1,k0)
        MFMA_PH(1, afr1, bk1)                 // ph3 (m1,k1)

        // boundary gate + publish tile tau+1
        asm volatile("s_waitcnt lgkmcnt(0)" ::: "memory");
        if (tau < 62) {
            asm volatile("s_waitcnt vmcnt(4)" ::: "memory");
        } else {
            asm volatile("s_waitcnt vmcnt(0)" ::: "memory");
        }
        __builtin_amdgcn_sched_barrier(0);
        __builtin_amdgcn_s_barrier();
        __builtin_amdgcn_sched_barrier(0);
    }

    // epilogue: C/D layout col = lane&15, row = khi*4 + j
    const size_t crow = (size_t)(tm * 256 + wr * 128 + khi * 4);
    const int    ccol = tn * 256 + wc * 64 + fr;
#pragma unroll
    for (int m = 0; m < 8; ++m)
#pragma unroll
        for (int n = 0; n < 4; ++n) {
            float* cp = C + (crow + m * 16) * N_OUT + (ccol + n * 16);
#pragma unroll
            for (int j = 0; j < 4; ++j)
                cp[(size_t)j * N_OUT] = acc[m][n][j];
        }
}

// ---------------- fallback fp32 GEMM (only if ws too small) ----------------
__global__ __launch_bounds__(256) void fb_gemm(const float* __restrict__ X,
                                               const float* __restrict__ W,
                                               const double* __restrict__ sum,
                                               float* __restrict__ C) {
    __shared__ float Xs[64][33];
    __shared__ float Ws[64][33];
    const float gamma = (float)(*sum / NW);
    const float denom = gamma + 1e-8f;
    const int tid = threadIdx.x;
    const int bm = blockIdx.y * 64;
    const int bn = blockIdx.x * 64;
    const int tr = tid >> 4, tc = tid & 15;
    const int lrow = tid >> 2;
    const int lcol = (tid & 3) * 8;
    float acc[4][4] = {};
    for (int k0 = 0; k0 < K_DIM; k0 += 32) {
        const float4* xs = (const float4*)(X + (size_t)(bm + lrow) * K_DIM + k0 + lcol);
        float4 v0 = xs[0], v1 = xs[1];
        Xs[lrow][lcol + 0] = v0.x; Xs[lrow][lcol + 1] = v0.y;
        Xs[lrow][lcol + 2] = v0.z; Xs[lrow][lcol + 3] = v0.w;
        Xs[lrow][lcol + 4] = v1.x; Xs[lrow][lcol + 5] = v1.y;
        Xs[lrow][lcol + 6] = v1.z; Xs[lrow][lcol + 7] = v1.w;
        const float4* wsrc = (const float4*)(W + (size_t)(bn + lrow) * K_DIM + k0 + lcol);
        float4 w0 = wsrc[0], w1 = wsrc[1];
        Ws[lrow][lcol + 0] = fminf(1.f, fmaxf(-1.f, rintf(w0.x / denom)));
        Ws[lrow][lcol + 1] = fminf(1.f, fmaxf(-1.f, rintf(w0.y / denom)));
        Ws[lrow][lcol + 2] = fminf(1.f, fmaxf(-1.f, rintf(w0.z / denom)));
        Ws[lrow][lcol + 3] = fminf(1.f, fmaxf(-1.f, rintf(w0.w / denom)));
        Ws[lrow][lcol + 4] = fminf(1.f, fmaxf(-1.f, rintf(w1.x / denom)));
        Ws[lrow][lcol + 5] = fminf(1.f, fmaxf(-1.f, rintf(w1.y / denom)));
        Ws[lrow][lcol + 6] = fminf(1.f, fmaxf(-1.f, rintf(w1.z / denom)));
        Ws[lrow][lcol + 7] = fminf(1.f, fmaxf(-1.f, rintf(w1.w / denom)));
        __syncthreads();
#pragma unroll 8
        for (int kk = 0; kk < 32; ++kk) {
            float a0 = Xs[tr * 4 + 0][kk], a1 = Xs[tr * 4 + 1][kk];
            float a2 = Xs[tr * 4 + 2][kk], a3 = Xs[tr * 4 + 3][kk];
            float b0 = Ws[tc * 4 + 0][kk], b1 = Ws[tc * 4 + 1][kk];
            float b2 = Ws[tc * 4 + 2][kk], b3 = Ws[tc * 4 + 3][kk];
            acc[0][0] += a0 * b0; acc[0][1] += a0 * b1; acc[0][2] += a0 * b2; acc[0][3] += a0 * b3;
            acc[1][0] += a1 * b0; acc[1][1] += a1 * b1; acc[1][2] += a1 * b2; acc[1][3] += a1 * b3;
            acc[2][0] += a2 * b0; acc[2][1] += a2 * b1; acc[2][2] += a2 * b2; acc[2][3] += a2 * b3;
            acc[3][0] += a3 * b0; acc[3][1] += a3 * b1; acc[3][2] += a3 * b2; acc[3][3] += a3 * b3;
        }
        __syncthreads();
    }
#pragma unroll
    for (int i = 0; i < 4; ++i)
#pragma unroll
        for (int j = 0; j < 4; ++j)
            C[(size_t)(bm + tr * 4 + i) * N_OUT + (bn + tc * 4 + j)] = acc[i][j];
}

extern "C" void kernel_launch(void* const* d_in, const int* in_sizes, int n_in,
                              void* d_out, int out_size, void* d_ws, size_t ws_size,
                              hipStream_t stream) {
    (void)in_sizes; (void)n_in; (void)out_size;
    const float* x = (const float*)d_in[0];
    const float* w = (const float*)d_in[1];
    float* out = (float*)d_out;
    float* scalars = out + (size_t)M_ROWS * N_OUT;   // [t_current, entropy]

    double* sum = (double*)d_ws;
    unsigned int* counts = (unsigned int*)((char*)d_ws + 8);
    unsigned short* xb = (unsigned short*)((char*)d_ws + 64);
    unsigned short* wq = (unsigned short*)((char*)d_ws + 64 + (size_t)M_ROWS * K_DIM * 2);

    const size_t need = 64 + (size_t)M_ROWS * K_DIM * 2 + (size_t)N_OUT * K_DIM * 2;
    const int fast = (ws_size >= need);

    hipMemsetAsync(d_ws, 0, 16, stream);
    k_gamma<<<1024, 256, 0, stream>>>(w, sum);

    if (fast) {
        k_cvt<<<2048, 256, 0, stream>>>(x, xb);
        k_quant<<<1024, 256, 0, stream>>>(w, sum, wq, counts, 1);
        k_fin<<<1, 1, 0, stream>>>(counts, scalars);
        hipFuncSetAttribute(reinterpret_cast<const void*>(k_gemm2),
                            hipFuncAttributeMaxDynamicSharedMemorySize, 131072);
        k_gemm2<<<dim3(512), 512, 131072, stream>>>(xb, wq, out);
    } else {
        k_quant<<<1024, 256, 0, stream>>>(w, sum, nullptr, counts, 0);
        k_fin<<<1, 1, 0, stream>>>(counts, scalars);
        dim3 grid(N_OUT / 64, M_ROWS / 64);
        fb_gemm<<<grid, 256, 0, stream>>>(x, w, sum, out);
    }
}

// Round 9
// 368.735 us; speedup vs baseline: 1.0084x; 1.0084x over previous
//
#include <hip/hip_runtime.h>
#include <stdint.h>

typedef short bf16x8 __attribute__((ext_vector_type(8)));
typedef float f32x4 __attribute__((ext_vector_type(4)));

#define M_ROWS 8192
#define N_OUT  4096
#define K_DIM  4096
#define NW     16777216.0   // number of weights

// ---------------- async global->LDS (16B per lane) ----------------
__device__ __forceinline__ void gload16(const void* g, void* l) {
    __builtin_amdgcn_global_load_lds((const __attribute__((address_space(1))) void*)g,
                                     (__attribute__((address_space(3))) void*)l,
                                     16, 0, 0);
}

// RNE f32 -> bf16 bits
__device__ __forceinline__ unsigned short f2bf(float f) {
    unsigned u = __float_as_uint(f);
    unsigned r = 0x7FFFu + ((u >> 16) & 1u);
    return (unsigned short)((u + r) >> 16);
}

// ---------------- gamma = sum |w| (double accumulation) ----------------
__global__ __launch_bounds__(256) void k_gamma(const float* __restrict__ w,
                                               double* __restrict__ sum) {
    const int n4 = (K_DIM * N_OUT) / 4;
    int idx = blockIdx.x * blockDim.x + threadIdx.x;
    int stride = gridDim.x * blockDim.x;
    const float4* w4 = (const float4*)w;
    double local = 0.0;
    for (int i = idx; i < n4; i += stride) {
        float4 v = w4[i];
        local += (double)fabsf(v.x) + (double)fabsf(v.y) +
                 (double)fabsf(v.z) + (double)fabsf(v.w);
    }
    __shared__ double sm[256];
    sm[threadIdx.x] = local;
    __syncthreads();
    for (int s = 128; s > 0; s >>= 1) {
        if (threadIdx.x < s) sm[threadIdx.x] += sm[threadIdx.x + s];
        __syncthreads();
    }
    if (threadIdx.x == 0) atomicAdd(sum, sm[0]);
}

// ---------------- quantize W -> ternary bf16 + bin counts ----------------
__global__ __launch_bounds__(256) void k_quant(const float* __restrict__ w,
                                               const double* __restrict__ sum,
                                               unsigned short* __restrict__ wq,
                                               unsigned int* __restrict__ counts,
                                               int do_store) {
    const float gamma = (float)(*sum / NW);
    const float denom = gamma + 1e-8f;
    const int n4 = (K_DIM * N_OUT) / 4;
    int idx = blockIdx.x * blockDim.x + threadIdx.x;
    int stride = gridDim.x * blockDim.x;
    const float4* w4 = (const float4*)w;
    unsigned cm = 0, cp = 0;
    for (int i = idx; i < n4; i += stride) {
        float4 v = w4[i];
        float q0 = fminf(1.f, fmaxf(-1.f, rintf(v.x / denom)));
        float q1 = fminf(1.f, fmaxf(-1.f, rintf(v.y / denom)));
        float q2 = fminf(1.f, fmaxf(-1.f, rintf(v.z / denom)));
        float q3 = fminf(1.f, fmaxf(-1.f, rintf(v.w / denom)));
        cm += (q0 < -0.5f) + (q1 < -0.5f) + (q2 < -0.5f) + (q3 < -0.5f);
        cp += (q0 >  0.5f) + (q1 >  0.5f) + (q2 >  0.5f) + (q3 >  0.5f);
        if (do_store) {
            unsigned b0 = (q0 < -0.5f) ? 0xBF80u : (q0 > 0.5f ? 0x3F80u : 0u);
            unsigned b1 = (q1 < -0.5f) ? 0xBF80u : (q1 > 0.5f ? 0x3F80u : 0u);
            unsigned b2 = (q2 < -0.5f) ? 0xBF80u : (q2 > 0.5f ? 0x3F80u : 0u);
            unsigned b3 = (q3 < -0.5f) ? 0xBF80u : (q3 > 0.5f ? 0x3F80u : 0u);
            uint2 pk;
            pk.x = b0 | (b1 << 16);
            pk.y = b2 | (b3 << 16);
            ((uint2*)wq)[i] = pk;
        }
    }
    __shared__ unsigned smc[512];
    smc[threadIdx.x] = cm;
    smc[256 + threadIdx.x] = cp;
    __syncthreads();
    for (int s = 128; s > 0; s >>= 1) {
        if (threadIdx.x < s) {
            smc[threadIdx.x] += smc[threadIdx.x + s];
            smc[256 + threadIdx.x] += smc[256 + threadIdx.x + s];
        }
        __syncthreads();
    }
    if (threadIdx.x == 0) {
        atomicAdd(&counts[0], smc[0]);
        atomicAdd(&counts[1], smc[256]);
    }
}

// ---------------- x f32 -> bf16 ----------------
__global__ __launch_bounds__(256) void k_cvt(const float* __restrict__ x,
                                             unsigned short* __restrict__ xb) {
    const int n4 = (M_ROWS * K_DIM) / 4;
    int idx = blockIdx.x * blockDim.x + threadIdx.x;
    int stride = gridDim.x * blockDim.x;
    const float4* x4 = (const float4*)x;
    for (int i = idx; i < n4; i += stride) {
        float4 v = x4[i];
        uint2 pk;
        pk.x = (unsigned)f2bf(v.x) | ((unsigned)f2bf(v.y) << 16);
        pk.y = (unsigned)f2bf(v.z) | ((unsigned)f2bf(v.w) << 16);
        ((uint2*)xb)[i] = pk;
    }
}

// ---------------- entropy + t_current ----------------
__global__ void k_fin(const unsigned int* __restrict__ counts,
                      float* __restrict__ outs) {
    double n = NW;
    double c1 = (double)counts[0];
    double c2 = (double)counts[1];
    double c0 = n - c1 - c2;
    double H = 0.0;
    if (c1 > 0.0) { double p = c1 / n; H -= p * log2(p); }
    if (c0 > 0.0) { double p = c0 / n; H -= p * log2(p); }
    if (c2 > 0.0) { double p = c2 / n; H -= p * log2(p); }
    float Hf = (float)H;
    float heat = 100.0f * fmaxf(Hf, 0.0f);
    outs[0] = -10.0f + (50.0f + heat) * 0.5f;
    outs[1] = Hf;
}

// ========== 256x256 bf16 MFMA GEMM, pipelined 4-phase per K-tile ==========
// Kernel body IDENTICAL to R8 (race-verified, absmax 1.0) except the
// block->tile mapping (one-variable experiment, feed-bound theory).
//
// R9 mapping: resident 256 blocks form a 16tm x 16tn square.
//   x = lin&7 (XCD), j = lin>>3.
//   tm = 16*(x&1) + (j&15)   -> XCD's L2 A-working-set: 16 panels x 32KB/t
//   tn = 4*(x>>1) + (j>>4)   -> 2 tn resident per XCD (64KB/t), B L2-resident
// Chip-wide unique operand bytes per K-step: ~1MB (vs 8MB with the old
// one-tn-per-XCD mapping where all 8 XCDs streamed the same A panels
// through L3/HBM independently). Predicted: FETCH_SIZE 680->~300MB,
// feed stops co-binding, LDS/MFMA floor ~2800-3300 cyc/K-step.

__device__ __forceinline__ void stage_half(const unsigned short* __restrict__ A,
                                           const unsigned short* __restrict__ B,
                                           char* lds, int H, int tm, int tn,
                                           int tid) {
    const int kt = H >> 2;
    const int q  = H & 3;                      // 0=A0 1=A1 2=B0 3=B1
    const unsigned short* src = (q & 2) ? B : A;
    const int rb = ((q & 2) ? tn : tm) * 256 + (q & 1) * 128;
    const int row = rb + ((tid >> 6) << 4) + (tid & 15);
    const unsigned short* g0 = src + (size_t)row * K_DIM + kt * 64 + ((tid >> 4) & 3) * 8;
    char* d = lds + ((size_t)(kt & 1) << 16) + (q << 14) + tid * 16;
    gload16(g0, d);              // ks=0: cols [khi*8, +8)
    gload16(g0 + 32, d + 8192);  // ks=1: cols [32+khi*8, +8)
}

// 16 MFMAs: one m-half x full n at one K-half; compiler inserts counted lgkm wait
#define MFMA_PH(MH, AF, BF)                                                    \
    __builtin_amdgcn_s_setprio(1);                                             \
    _Pragma("unroll") for (int mm = 0; mm < 4; ++mm)                           \
    _Pragma("unroll") for (int nn = 0; nn < 4; ++nn)                           \
        acc[(MH)*4 + mm][nn] = __builtin_amdgcn_mfma_f32_16x16x32_bf16(        \
            AF[mm], BF[nn], acc[(MH)*4 + mm][nn], 0, 0, 0);                    \
    __builtin_amdgcn_s_setprio(0);

__global__ __launch_bounds__(512, 2) void k_gemm2(const unsigned short* __restrict__ A,
                                                  const unsigned short* __restrict__ B,
                                                  float* __restrict__ C) {
    extern __shared__ char smem[];
    const int tid  = threadIdx.x;
    const int lane = tid & 63;
    const int wid  = tid >> 6;
    const int wr   = wid >> 2;        // 0..1  (M)
    const int wc   = wid & 3;         // 0..3  (N)
    const int fr   = lane & 15;
    const int khi  = lane >> 4;       // 0..3

    // R9 XCD/L2-locality mapping (bijective: (x&1,j&15)->tm, (x>>1,j>>4)->tn)
    const int lin = blockIdx.x;
    const int x   = lin & 7;
    const int j   = lin >> 3;
    const int tm  = ((x & 1) << 4) + (j & 15);   // 0..31
    const int tn  = ((x >> 1) << 2) + (j >> 4);  // 0..15

    f32x4 acc[8][4] = {};

    // prologue: tile0 all halves + B0,B1 of tile1; drain; publish
    stage_half(A, B, smem, 0, tm, tn, tid);
    stage_half(A, B, smem, 1, tm, tn, tid);
    stage_half(A, B, smem, 2, tm, tn, tid);
    stage_half(A, B, smem, 3, tm, tn, tid);
    stage_half(A, B, smem, 6, tm, tn, tid);
    stage_half(A, B, smem, 7, tm, tn, tid);
    asm volatile("s_waitcnt vmcnt(0)" ::: "memory");
    __builtin_amdgcn_s_barrier();

    bf16x8 afr0[4], afr1[4], bk0[4], bk1[4];
    const int bsel = (wc & 1) * 4;    // fragment group within B-half

    for (int tau = 0; tau < 64; ++tau) {
        const char* aptr = smem + ((size_t)(tau & 1) << 16) + ((size_t)wr << 14) + lane * 16;
        const char* bptr = smem + ((size_t)(tau & 1) << 16) + 32768 + ((size_t)(wc >> 1) << 14)
                         + bsel * 1024 + lane * 16;
        const int g = tau * 4;

        // issue ph0 reads: A(m0,k0) + B(k0)
#pragma unroll
        for (int mm = 0; mm < 4; ++mm)
            afr0[mm] = *(const bf16x8*)(aptr + (0 * 8 + mm) * 1024);
#pragma unroll
        for (int nn = 0; nn < 4; ++nn)
            bk0[nn] = *(const bf16x8*)(bptr + (0 * 8 + nn) * 1024);
        if (g + 4 < 256) stage_half(A, B, smem, g + 4, tm, tn, tid);
        // issue ph1 reads ahead: A(m0,k1) + B(k1)
#pragma unroll
        for (int mm = 0; mm < 4; ++mm)
            afr1[mm] = *(const bf16x8*)(aptr + (1 * 8 + mm) * 1024);
#pragma unroll
        for (int nn = 0; nn < 4; ++nn)
            bk1[nn] = *(const bf16x8*)(bptr + (1 * 8 + nn) * 1024);

        MFMA_PH(0, afr0, bk0)                 // ph0 (m0,k0)

        // issue ph2 reads ahead: A(m1,k0)
#pragma unroll
        for (int mm = 0; mm < 4; ++mm)
            afr0[mm] = *(const bf16x8*)(aptr + (0 * 8 + 4 + mm) * 1024);
        if (g + 5 < 256) stage_half(A, B, smem, g + 5, tm, tn, tid);

        MFMA_PH(0, afr1, bk1)                 // ph1 (m0,k1)

        // issue ph3 reads ahead: A(m1,k1)
#pragma unroll
        for (int mm = 0; mm < 4; ++mm)
            afr1[mm] = *(const bf16x8*)(aptr + (1 * 8 + 4 + mm) * 1024);

        // mid fence: 8 newest outstanding lgkm = the A(m1,*) reads just issued
        asm volatile("s_waitcnt lgkmcnt(8)" ::: "memory");
        __builtin_amdgcn_sched_barrier(0);
        __builtin_amdgcn_s_barrier();
        __builtin_amdgcn_sched_barrier(0);
        if (g + 10 < 256) stage_half(A, B, smem, g + 10, tm, tn, tid);
        if (g + 11 < 256) stage_half(A, B, smem, g + 11, tm, tn, tid);

        MFMA_PH(1, afr0, bk0)                 // ph2 (m1,k0)
        MFMA_PH(1, afr1, bk1)                 // ph3 (m1,k1)

        // boundary gate + publish tile tau+1
        asm volatile("s_waitcnt lgkmcnt(0)" ::: "memory");
        if (tau < 62) {
            asm volatile("s_waitcnt vmcnt(4)" ::: "memory");
        } else {
            asm volatile("s_waitcnt vmcnt(0)" ::: "memory");
        }
        __builtin_amdgcn_sched_barrier(0);
        __builtin_amdgcn_s_barrier();
        __builtin_amdgcn_sched_barrier(0);
    }

    // epilogue: C/D layout col = lane&15, row = khi*4 + j
    const size_t crow = (size_t)(tm * 256 + wr * 128 + khi * 4);
    const int    ccol = tn * 256 + wc * 64 + fr;
#pragma unroll
    for (int m = 0; m < 8; ++m)
#pragma unroll
        for (int n = 0; n < 4; ++n) {
            float* cp = C + (crow + m * 16) * N_OUT + (ccol + n * 16);
#pragma unroll
            for (int jj = 0; jj < 4; ++jj)
                cp[(size_t)jj * N_OUT] = acc[m][n][jj];
        }
}

// ---------------- fallback fp32 GEMM (only if ws too small) ----------------
__global__ __launch_bounds__(256) void fb_gemm(const float* __restrict__ X,
                                               const float* __restrict__ W,
                                               const double* __restrict__ sum,
                                               float* __restrict__ C) {
    __shared__ float Xs[64][33];
    __shared__ float Ws[64][33];
    const float gamma = (float)(*sum / NW);
    const float denom = gamma + 1e-8f;
    const int tid = threadIdx.x;
    const int bm = blockIdx.y * 64;
    const int bn = blockIdx.x * 64;
    const int tr = tid >> 4, tc = tid & 15;
    const int lrow = tid >> 2;
    const int lcol = (tid & 3) * 8;
    float acc[4][4] = {};
    for (int k0 = 0; k0 < K_DIM; k0 += 32) {
        const float4* xs = (const float4*)(X + (size_t)(bm + lrow) * K_DIM + k0 + lcol);
        float4 v0 = xs[0], v1 = xs[1];
        Xs[lrow][lcol + 0] = v0.x; Xs[lrow][lcol + 1] = v0.y;
        Xs[lrow][lcol + 2] = v0.z; Xs[lrow][lcol + 3] = v0.w;
        Xs[lrow][lcol + 4] = v1.x; Xs[lrow][lcol + 5] = v1.y;
        Xs[lrow][lcol + 6] = v1.z; Xs[lrow][lcol + 7] = v1.w;
        const float4* wsrc = (const float4*)(W + (size_t)(bn + lrow) * K_DIM + k0 + lcol);
        float4 w0 = wsrc[0], w1 = wsrc[1];
        Ws[lrow][lcol + 0] = fminf(1.f, fmaxf(-1.f, rintf(w0.x / denom)));
        Ws[lrow][lcol + 1] = fminf(1.f, fmaxf(-1.f, rintf(w0.y / denom)));
        Ws[lrow][lcol + 2] = fminf(1.f, fmaxf(-1.f, rintf(w0.z / denom)));
        Ws[lrow][lcol + 3] = fminf(1.f, fmaxf(-1.f, rintf(w0.w / denom)));
        Ws[lrow][lcol + 4] = fminf(1.f, fmaxf(-1.f, rintf(w1.x / denom)));
        Ws[lrow][lcol + 5] = fminf(1.f, fmaxf(-1.f, rintf(w1.y / denom)));
        Ws[lrow][lcol + 6] = fminf(1.f, fmaxf(-1.f, rintf(w1.z / denom)));
        Ws[lrow][lcol + 7] = fminf(1.f, fmaxf(-1.f, rintf(w1.w / denom)));
        __syncthreads();
#pragma unroll 8
        for (int kk = 0; kk < 32; ++kk) {
            float a0 = Xs[tr * 4 + 0][kk], a1 = Xs[tr * 4 + 1][kk];
            float a2 = Xs[tr * 4 + 2][kk], a3 = Xs[tr * 4 + 3][kk];
            float b0 = Ws[tc * 4 + 0][kk], b1 = Ws[tc * 4 + 1][kk];
            float b2 = Ws[tc * 4 + 2][kk], b3 = Ws[tc * 4 + 3][kk];
            acc[0][0] += a0 * b0; acc[0][1] += a0 * b1; acc[0][2] += a0 * b2; acc[0][3] += a0 * b3;
            acc[1][0] += a1 * b0; acc[1][1] += a1 * b1; acc[1][2] += a1 * b2; acc[1][3] += a1 * b3;
            acc[2][0] += a2 * b0; acc[2][1] += a2 * b1; acc[2][2] += a2 * b2; acc[2][3] += a2 * b3;
            acc[3][0] += a3 * b0; acc[3][1] += a3 * b1; acc[3][2] += a3 * b2; acc[3][3] += a3 * b3;
        }
        __syncthreads();
    }
#pragma unroll
    for (int i = 0; i < 4; ++i)
#pragma unroll
        for (int jj = 0; jj < 4; ++jj)
            C[(size_t)(bm + tr * 4 + i) * N_OUT + (bn + tc * 4 + jj)] = acc[i][jj];
}

extern "C" void kernel_launch(void* const* d_in, const int* in_sizes, int n_in,
                              void* d_out, int out_size, void* d_ws, size_t ws_size,
                              hipStream_t stream) {
    (void)in_sizes; (void)n_in; (void)out_size;
    const float* x = (const float*)d_in[0];
    const float* w = (const float*)d_in[1];
    float* out = (float*)d_out;
    float* scalars = out + (size_t)M_ROWS * N_OUT;   // [t_current, entropy]

    double* sum = (double*)d_ws;
    unsigned int* counts = (unsigned int*)((char*)d_ws + 8);
    unsigned short* xb = (unsigned short*)((char*)d_ws + 64);
    unsigned short* wq = (unsigned short*)((char*)d_ws + 64 + (size_t)M_ROWS * K_DIM * 2);

    const size_t need = 64 + (size_t)M_ROWS * K_DIM * 2 + (size_t)N_OUT * K_DIM * 2;
    const int fast = (ws_size >= need);

    hipMemsetAsync(d_ws, 0, 16, stream);
    k_gamma<<<1024, 256, 0, stream>>>(w, sum);

    if (fast) {
        k_cvt<<<2048, 256, 0, stream>>>(x, xb);
        k_quant<<<1024, 256, 0, stream>>>(w, sum, wq, counts, 1);
        k_fin<<<1, 1, 0, stream>>>(counts, scalars);
        hipFuncSetAttribute(reinterpret_cast<const void*>(k_gemm2),
                            hipFuncAttributeMaxDynamicSharedMemorySize, 131072);
        k_gemm2<<<dim3(512), 512, 131072, stream>>>(xb, wq, out);
    } else {
        k_quant<<<1024, 256, 0, stream>>>(w, sum, nullptr, counts, 0);
        k_fin<<<1, 1, 0, stream>>>(counts, scalars);
        dim3 grid(N_OUT / 64, M_ROWS / 64);
        fb_gemm<<<grid, 256, 0, stream>>>(x, w, sum, out);
    }
}

// Round 11
// 367.854 us; speedup vs baseline: 1.0108x; 1.0024x over previous
//
#include <hip/hip_runtime.h>
#include <stdint.h>

typedef short bf16x8 __attribute__((ext_vector_type(8)));
typedef float f32x4 __attribute__((ext_vector_type(4)));

#define M_ROWS 8192
#define N_OUT  4096
#define K_DIM  4096
#define NW     16777216.0   // number of weights

// ---------------- async global->LDS (16B per lane) ----------------
__device__ __forceinline__ void gload16(const void* g, void* l) {
    __builtin_amdgcn_global_load_lds((const __attribute__((address_space(1))) void*)g,
                                     (__attribute__((address_space(3))) void*)l,
                                     16, 0, 0);
}

// RNE f32 -> bf16 bits
__device__ __forceinline__ unsigned short f2bf(float f) {
    unsigned u = __float_as_uint(f);
    unsigned r = 0x7FFFu + ((u >> 16) & 1u);
    return (unsigned short)((u + r) >> 16);
}

// ---------------- gamma = sum |w| (double accumulation) ----------------
__global__ __launch_bounds__(256) void k_gamma(const float* __restrict__ w,
                                               double* __restrict__ sum) {
    const int n4 = (K_DIM * N_OUT) / 4;
    int idx = blockIdx.x * blockDim.x + threadIdx.x;
    int stride = gridDim.x * blockDim.x;
    const float4* w4 = (const float4*)w;
    double local = 0.0;
    for (int i = idx; i < n4; i += stride) {
        float4 v = w4[i];
        local += (double)fabsf(v.x) + (double)fabsf(v.y) +
                 (double)fabsf(v.z) + (double)fabsf(v.w);
    }
    __shared__ double sm[256];
    sm[threadIdx.x] = local;
    __syncthreads();
    for (int s = 128; s > 0; s >>= 1) {
        if (threadIdx.x < s) sm[threadIdx.x] += sm[threadIdx.x + s];
        __syncthreads();
    }
    if (threadIdx.x == 0) atomicAdd(sum, sm[0]);
}

// ---------------- quantize W -> ternary bf16 + bin counts ----------------
__global__ __launch_bounds__(256) void k_quant(const float* __restrict__ w,
                                               const double* __restrict__ sum,
                                               unsigned short* __restrict__ wq,
                                               unsigned int* __restrict__ counts,
                                               int do_store) {
    const float gamma = (float)(*sum / NW);
    const float denom = gamma + 1e-8f;
    const int n4 = (K_DIM * N_OUT) / 4;
    int idx = blockIdx.x * blockDim.x + threadIdx.x;
    int stride = gridDim.x * blockDim.x;
    const float4* w4 = (const float4*)w;
    unsigned cm = 0, cp = 0;
    for (int i = idx; i < n4; i += stride) {
        float4 v = w4[i];
        float q0 = fminf(1.f, fmaxf(-1.f, rintf(v.x / denom)));
        float q1 = fminf(1.f, fmaxf(-1.f, rintf(v.y / denom)));
        float q2 = fminf(1.f, fmaxf(-1.f, rintf(v.z / denom)));
        float q3 = fminf(1.f, fmaxf(-1.f, rintf(v.w / denom)));
        cm += (q0 < -0.5f) + (q1 < -0.5f) + (q2 < -0.5f) + (q3 < -0.5f);
        cp += (q0 >  0.5f) + (q1 >  0.5f) + (q2 >  0.5f) + (q3 >  0.5f);
        if (do_store) {
            unsigned b0 = (q0 < -0.5f) ? 0xBF80u : (q0 > 0.5f ? 0x3F80u : 0u);
            unsigned b1 = (q1 < -0.5f) ? 0xBF80u : (q1 > 0.5f ? 0x3F80u : 0u);
            unsigned b2 = (q2 < -0.5f) ? 0xBF80u : (q2 > 0.5f ? 0x3F80u : 0u);
            unsigned b3 = (q3 < -0.5f) ? 0xBF80u : (q3 > 0.5f ? 0x3F80u : 0u);
            uint2 pk;
            pk.x = b0 | (b1 << 16);
            pk.y = b2 | (b3 << 16);
            ((uint2*)wq)[i] = pk;
        }
    }
    __shared__ unsigned smc[512];
    smc[threadIdx.x] = cm;
    smc[256 + threadIdx.x] = cp;
    __syncthreads();
    for (int s = 128; s > 0; s >>= 1) {
        if (threadIdx.x < s) {
            smc[threadIdx.x] += smc[threadIdx.x + s];
            smc[256 + threadIdx.x] += smc[256 + threadIdx.x + s];
        }
        __syncthreads();
    }
    if (threadIdx.x == 0) {
        atomicAdd(&counts[0], smc[0]);
        atomicAdd(&counts[1], smc[256]);
    }
}

// ---------------- x f32 -> bf16 ----------------
__global__ __launch_bounds__(256) void k_cvt(const float* __restrict__ x,
                                             unsigned short* __restrict__ xb) {
    const int n4 = (M_ROWS * K_DIM) / 4;
    int idx = blockIdx.x * blockDim.x + threadIdx.x;
    int stride = gridDim.x * blockDim.x;
    const float4* x4 = (const float4*)x;
    for (int i = idx; i < n4; i += stride) {
        float4 v = x4[i];
        uint2 pk;
        pk.x = (unsigned)f2bf(v.x) | ((unsigned)f2bf(v.y) << 16);
        pk.y = (unsigned)f2bf(v.z) | ((unsigned)f2bf(v.w) << 16);
        ((uint2*)xb)[i] = pk;
    }
}

// ---------------- entropy + t_current ----------------
__global__ void k_fin(const unsigned int* __restrict__ counts,
                      float* __restrict__ outs) {
    double n = NW;
    double c1 = (double)counts[0];
    double c2 = (double)counts[1];
    double c0 = n - c1 - c2;
    double H = 0.0;
    if (c1 > 0.0) { double p = c1 / n; H -= p * log2(p); }
    if (c0 > 0.0) { double p = c0 / n; H -= p * log2(p); }
    if (c2 > 0.0) { double p = c2 / n; H -= p * log2(p); }
    float Hf = (float)H;
    float heat = 100.0f * fmaxf(Hf, 0.0f);
    outs[0] = -10.0f + (50.0f + heat) * 0.5f;
    outs[1] = Hf;
}

// ===== 256x256 bf16 MFMA GEMM, 8-phase / 2-Ktile iter (R11: fixed stages) =====
// C[M,N] = A[M,K] * B[N,K]^T. 512 threads = 8 waves (2M x 4N), per-wave 128x64.
// LDS 128KB: buf[2] x {A0,A1,B0,B1} slots (16KB), fragment-major (0 conflicts,
// measured R5). R9 XCD mapping (FETCH 307MB, measured).
//
// SLOT READER MAP (the R10 bug): wave wr reads A-slot wr ONLY; rows 0-63 at
// the tile's first A-read phase, rows 64-127 at its second. So even-buf:
//   A slots last read ph2 -> stage >= ph3 ; B slots last read ph1 -> >= ph2
// odd-buf: A last read ph6 ; B last read ph5.
// (phase-p reads retire globally at p's closing barrier: per-wave lgkmcnt(0)
//  precedes it.)
//
// Stage stream (1/phase), all constraints satisfied:
//   ph0:T(o).A0  ph1:T(o).A1  ph2:T(e+2).B0  ph3:T(e+2).B1
//   ph4:T(e+2).A0 ph5:T(e+2).A1 ph6:T(o+2).B0 ph7:T(o+2).B1
//   (T(o).A* staged at the top of the iteration that reads them at ph4-7)
// Gates: vmcnt(4) (=2 stages in flight) at ph3 & ph7 ONLY.
//   ph3 FIFO: newest {T(e+2).B1,B0} fly; T(o).{A1,A0} + T(o).{B1,B0} (prev
//   ph7/ph6) landed -> ph4-7 safe.
//   ph7 FIFO: newest {T(o+2).B1,B0} fly; T(e+2).{A1,A0,B1,B0} landed -> next
//   ph0-3 safe. Last iter (it=31): ph2-7 stages guarded off -> vmcnt(0).
// Phase body: [reads][stage][bar][lgkmcnt(0)][setprio+16 MFMA][bar] with the
// counted-vmcnt discipline (T3+T4): no per-tile full drains.

__device__ __forceinline__ void stage_half(const unsigned short* __restrict__ A,
                                           const unsigned short* __restrict__ B,
                                           char* lds, int H, int tm, int tn,
                                           int tid) {
    const int kt = H >> 2;
    const int q  = H & 3;                      // 0=A0 1=A1 2=B0 3=B1
    const unsigned short* src = (q & 2) ? B : A;
    const int rb = ((q & 2) ? tn : tm) * 256 + (q & 1) * 128;
    const int row = rb + ((tid >> 6) << 4) + (tid & 15);
    const unsigned short* g0 = src + (size_t)row * K_DIM + kt * 64 + ((tid >> 4) & 3) * 8;
    char* d = lds + ((size_t)(kt & 1) << 16) + (q << 14) + tid * 16;
    gload16(g0, d);              // ks=0
    gload16(g0 + 32, d + 8192);  // ks=1
}

#define MFMA_Q(ACCM, ACCN, AF, BF)                                             \
    __builtin_amdgcn_s_setprio(1);                                             \
    _Pragma("unroll") for (int mm = 0; mm < 4; ++mm)                           \
    _Pragma("unroll") for (int nn = 0; nn < 2; ++nn)                           \
    _Pragma("unroll") for (int ks = 0; ks < 2; ++ks)                           \
        acc[(ACCM) + mm][(ACCN) + nn] = __builtin_amdgcn_mfma_f32_16x16x32_bf16( \
            AF[mm][ks], BF[nn][ks], acc[(ACCM) + mm][(ACCN) + nn], 0, 0, 0);   \
    __builtin_amdgcn_s_setprio(0);

#define RD_A(PTR, BASE)                                                        \
    _Pragma("unroll") for (int mm = 0; mm < 4; ++mm)                           \
    _Pragma("unroll") for (int ks = 0; ks < 2; ++ks)                           \
        afr[mm][ks] = *(const bf16x8*)((PTR) + (ks * 8 + (BASE) + mm) * 1024);

#define RD_B(PTR, BASE, DST)                                                   \
    _Pragma("unroll") for (int nn = 0; nn < 2; ++nn)                           \
    _Pragma("unroll") for (int ks = 0; ks < 2; ++ks)                           \
        DST[nn][ks] = *(const bf16x8*)((PTR) + (ks * 8 + (BASE) + nn) * 1024);

#define BAR  __builtin_amdgcn_s_barrier()
#define LGKM0 asm volatile("s_waitcnt lgkmcnt(0)" ::: "memory")

__global__ __launch_bounds__(512, 2) void k_gemm2(const unsigned short* __restrict__ A,
                                                  const unsigned short* __restrict__ B,
                                                  float* __restrict__ C) {
    extern __shared__ char smem[];
    const int tid  = threadIdx.x;
    const int lane = tid & 63;
    const int wid  = tid >> 6;
    const int wr   = wid >> 2;        // 0..1  (M)
    const int wc   = wid & 3;         // 0..3  (N)
    const int fr   = lane & 15;
    const int khi  = lane >> 4;       // 0..3

    // R9 XCD/L2-locality mapping (bijective)
    const int lin = blockIdx.x;
    const int x   = lin & 7;
    const int j   = lin >> 3;
    const int tm  = ((x & 1) << 4) + (j & 15);   // 0..31
    const int tn  = ((x >> 1) << 2) + (j >> 4);  // 0..15

    f32x4 acc[8][4] = {};

    // prologue: T0 all 4 halves + T1.{B0,B1}; counted gate (T0 landed); publish
    stage_half(A, B, smem, 0, tm, tn, tid);   // T0.A0
    stage_half(A, B, smem, 1, tm, tn, tid);   // T0.A1
    stage_half(A, B, smem, 2, tm, tn, tid);   // T0.B0
    stage_half(A, B, smem, 3, tm, tn, tid);   // T0.B1
    stage_half(A, B, smem, 6, tm, tn, tid);   // T1.B0
    stage_half(A, B, smem, 7, tm, tn, tid);   // T1.B1
    asm volatile("s_waitcnt vmcnt(4)" ::: "memory");
    BAR;

    bf16x8 afr[4][2], b0[2][2], b1[2][2];
    const int bsel = (wc & 1) * 4;

    const char* aE = smem + ((size_t)wr << 14) + lane * 16;
    const char* bE = smem + 32768 + ((size_t)(wc >> 1) << 14) + bsel * 1024 + lane * 16;
    const char* aO = aE + 65536;
    const char* bO = bE + 65536;

    for (int it = 0; it < 32; ++it) {
        const int g = it * 8;             // H base (tile e = 2it)
        const bool more = (it < 31);

        // ---- ph0: reads E:A(rows0-63)+B(n0) [12]; stage T(o).A0
        RD_A(aE, 0)
        RD_B(bE, 0, b0)
        stage_half(A, B, smem, g + 4, tm, tn, tid);
        BAR; LGKM0;
        MFMA_Q(0, 0, afr, b0)
        BAR;

        // ---- ph1: reads E:B(n1) [4]; stage T(o).A1
        RD_B(bE, 2, b1)
        stage_half(A, B, smem, g + 5, tm, tn, tid);
        BAR; LGKM0;
        MFMA_Q(0, 2, afr, b1)
        BAR;

        // ---- ph2: reads E:A(rows64-127) [8]; stage T(e+2).B0
        RD_A(aE, 4)
        if (more) stage_half(A, B, smem, g + 10, tm, tn, tid);
        BAR; LGKM0;
        MFMA_Q(4, 2, afr, b1)
        BAR;

        // ---- ph3: no reads; stage T(e+2).B1; MFMA; GATE
        if (more) stage_half(A, B, smem, g + 11, tm, tn, tid);
        BAR; LGKM0;
        MFMA_Q(4, 0, afr, b0)
        if (more) { asm volatile("s_waitcnt vmcnt(4)" ::: "memory"); }
        else      { asm volatile("s_waitcnt vmcnt(0)" ::: "memory"); }
        BAR;

        // ---- ph4: reads O:A(rows0-63)+B(n0) [12]; stage T(e+2).A0
        RD_A(aO, 0)
        RD_B(bO, 0, b0)
        if (more) stage_half(A, B, smem, g + 8, tm, tn, tid);
        BAR; LGKM0;
        MFMA_Q(0, 0, afr, b0)
        BAR;

        // ---- ph5: reads O:B(n1) [4]; stage T(e+2).A1
        RD_B(bO, 2, b1)
        if (more) stage_half(A, B, smem, g + 9, tm, tn, tid);
        BAR; LGKM0;
        MFMA_Q(0, 2, afr, b1)
        BAR;

        // ---- ph6: reads O:A(rows64-127) [8]; stage T(o+2).B0
        RD_A(aO, 4)
        if (more) stage_half(A, B, smem, g + 14, tm, tn, tid);
        BAR; LGKM0;
        MFMA_Q(4, 2, afr, b1)
        BAR;

        // ---- ph7: no reads; stage T(o+2).B1; MFMA; GATE
        if (more) stage_half(A, B, smem, g + 15, tm, tn, tid);
        BAR; LGKM0;
        MFMA_Q(4, 0, afr, b0)
        if (more) { asm volatile("s_waitcnt vmcnt(4)" ::: "memory"); }
        else      { asm volatile("s_waitcnt vmcnt(0)" ::: "memory"); }
        BAR;
    }
    asm volatile("s_waitcnt vmcnt(0)" ::: "memory");

    // epilogue: C/D layout col = lane&15, row = khi*4 + j
    const size_t crow = (size_t)(tm * 256 + wr * 128 + khi * 4);
    const int    ccol = tn * 256 + wc * 64 + fr;
#pragma unroll
    for (int m = 0; m < 8; ++m)
#pragma unroll
        for (int n = 0; n < 4; ++n) {
            float* cp = C + (crow + m * 16) * N_OUT + (ccol + n * 16);
#pragma unroll
            for (int jj = 0; jj < 4; ++jj)
                cp[(size_t)jj * N_OUT] = acc[m][n][jj];
        }
}

// ---------------- fallback fp32 GEMM (only if ws too small) ----------------
__global__ __launch_bounds__(256) void fb_gemm(const float* __restrict__ X,
                                               const float* __restrict__ W,
                                               const double* __restrict__ sum,
                                               float* __restrict__ C) {
    __shared__ float Xs[64][33];
    __shared__ float Ws[64][33];
    const float gamma = (float)(*sum / NW);
    const float denom = gamma + 1e-8f;
    const int tid = threadIdx.x;
    const int bm = blockIdx.y * 64;
    const int bn = blockIdx.x * 64;
    const int tr = tid >> 4, tc = tid & 15;
    const int lrow = tid >> 2;
    const int lcol = (tid & 3) * 8;
    float acc[4][4] = {};
    for (int k0 = 0; k0 < K_DIM; k0 += 32) {
        const float4* xs = (const float4*)(X + (size_t)(bm + lrow) * K_DIM + k0 + lcol);
        float4 v0 = xs[0], v1 = xs[1];
        Xs[lrow][lcol + 0] = v0.x; Xs[lrow][lcol + 1] = v0.y;
        Xs[lrow][lcol + 2] = v0.z; Xs[lrow][lcol + 3] = v0.w;
        Xs[lrow][lcol + 4] = v1.x; Xs[lrow][lcol + 5] = v1.y;
        Xs[lrow][lcol + 6] = v1.z; Xs[lrow][lcol + 7] = v1.w;
        const float4* wsrc = (const float4*)(W + (size_t)(bn + lrow) * K_DIM + k0 + lcol);
        float4 w0 = wsrc[0], w1 = wsrc[1];
        Ws[lrow][lcol + 0] = fminf(1.f, fmaxf(-1.f, rintf(w0.x / denom)));
        Ws[lrow][lcol + 1] = fminf(1.f, fmaxf(-1.f, rintf(w0.y / denom)));
        Ws[lrow][lcol + 2] = fminf(1.f, fmaxf(-1.f, rintf(w0.z / denom)));
        Ws[lrow][lcol + 3] = fminf(1.f, fmaxf(-1.f, rintf(w0.w / denom)));
        Ws[lrow][lcol + 4] = fminf(1.f, fmaxf(-1.f, rintf(w1.x / denom)));
        Ws[lrow][lcol + 5] = fminf(1.f, fmaxf(-1.f, rintf(w1.y / denom)));
        Ws[lrow][lcol + 6] = fminf(1.f, fmaxf(-1.f, rintf(w1.z / denom)));
        Ws[lrow][lcol + 7] = fminf(1.f, fmaxf(-1.f, rintf(w1.w / denom)));
        __syncthreads();
#pragma unroll 8
        for (int kk = 0; kk < 32; ++kk) {
            float a0 = Xs[tr * 4 + 0][kk], a1 = Xs[tr * 4 + 1][kk];
            float a2 = Xs[tr * 4 + 2][kk], a3 = Xs[tr * 4 + 3][kk];
            float b0 = Ws[tc * 4 + 0][kk], b1 = Ws[tc * 4 + 1][kk];
            float b2 = Ws[tc * 4 + 2][kk], b3 = Ws[tc * 4 + 3][kk];
            acc[0][0] += a0 * b0; acc[0][1] += a0 * b1; acc[0][2] += a0 * b2; acc[0][3] += a0 * b3;
            acc[1][0] += a1 * b0; acc[1][1] += a1 * b1; acc[1][2] += a1 * b2; acc[1][3] += a1 * b3;
            acc[2][0] += a2 * b0; acc[2][1] += a2 * b1; acc[2][2] += a2 * b2; acc[2][3] += a2 * b3;
            acc[3][0] += a3 * b0; acc[3][1] += a3 * b1; acc[3][2] += a3 * b2; acc[3][3] += a3 * b3;
        }
        __syncthreads();
    }
#pragma unroll
    for (int i = 0; i < 4; ++i)
#pragma unroll
        for (int jj = 0; jj < 4; ++jj)
            C[(size_t)(bm + tr * 4 + i) * N_OUT + (bn + tc * 4 + jj)] = acc[i][jj];
}

extern "C" void kernel_launch(void* const* d_in, const int* in_sizes, int n_in,
                              void* d_out, int out_size, void* d_ws, size_t ws_size,
                              hipStream_t stream) {
    (void)in_sizes; (void)n_in; (void)out_size;
    const float* x = (const float*)d_in[0];
    const float* w = (const float*)d_in[1];
    float* out = (float*)d_out;
    float* scalars = out + (size_t)M_ROWS * N_OUT;   // [t_current, entropy]

    double* sum = (double*)d_ws;
    unsigned int* counts = (unsigned int*)((char*)d_ws + 8);
    unsigned short* xb = (unsigned short*)((char*)d_ws + 64);
    unsigned short* wq = (unsigned short*)((char*)d_ws + 64 + (size_t)M_ROWS * K_DIM * 2);

    const size_t need = 64 + (size_t)M_ROWS * K_DIM * 2 + (size_t)N_OUT * K_DIM * 2;
    const int fast = (ws_size >= need);

    hipMemsetAsync(d_ws, 0, 16, stream);
    k_gamma<<<1024, 256, 0, stream>>>(w, sum);

    if (fast) {
        k_cvt<<<2048, 256, 0, stream>>>(x, xb);
        k_quant<<<1024, 256, 0, stream>>>(w, sum, wq, counts, 1);
        k_fin<<<1, 1, 0, stream>>>(counts, scalars);
        hipFuncSetAttribute(reinterpret_cast<const void*>(k_gemm2),
                            hipFuncAttributeMaxDynamicSharedMemorySize, 131072);
        k_gemm2<<<dim3(512), 512, 131072, stream>>>(xb, wq, out);
    } else {
        k_quant<<<1024, 256, 0, stream>>>(w, sum, nullptr, counts, 0);
        k_fin<<<1, 1, 0, stream>>>(counts, scalars);
        dim3 grid(N_OUT / 64, M_ROWS / 64);
        fb_gemm<<<grid, 256, 0, stream>>>(x, w, sum, out);
    }
}

// Round 12
// 367.498 us; speedup vs baseline: 1.0117x; 1.0010x over previous
//
#include <hip/hip_runtime.h>
#include <stdint.h>

typedef short bf16x8 __attribute__((ext_vector_type(8)));
typedef float f32x4 __attribute__((ext_vector_type(4)));

#define M_ROWS 8192
#define N_OUT  4096
#define K_DIM  4096
#define NW     16777216.0   // number of weights

// ---------------- async global->LDS (16B per lane) ----------------
__device__ __forceinline__ void gload16(const void* g, void* l) {
    __builtin_amdgcn_global_load_lds((const __attribute__((address_space(1))) void*)g,
                                     (__attribute__((address_space(3))) void*)l,
                                     16, 0, 0);
}

// RNE f32 -> bf16 bits
__device__ __forceinline__ unsigned short f2bf(float f) {
    unsigned u = __float_as_uint(f);
    unsigned r = 0x7FFFu + ((u >> 16) & 1u);
    return (unsigned short)((u + r) >> 16);
}

// ------- fused: gamma partial-sum (W) + x f32->bf16 conversion -------
__global__ __launch_bounds__(256) void k_gamma_cvt(const float* __restrict__ w,
                                                   const float* __restrict__ x,
                                                   unsigned short* __restrict__ xb,
                                                   double* __restrict__ sum) {
    const int idx = blockIdx.x * blockDim.x + threadIdx.x;
    const int stride = gridDim.x * blockDim.x;

    // part 1: abs-sum of W (double accumulation)
    const int wn4 = (K_DIM * N_OUT) / 4;
    const float4* w4 = (const float4*)w;
    double local = 0.0;
    for (int i = idx; i < wn4; i += stride) {
        float4 v = w4[i];
        local += (double)fabsf(v.x) + (double)fabsf(v.y) +
                 (double)fabsf(v.z) + (double)fabsf(v.w);
    }

    // part 2: convert x
    const int xn4 = (M_ROWS * K_DIM) / 4;
    const float4* x4 = (const float4*)x;
    for (int i = idx; i < xn4; i += stride) {
        float4 v = x4[i];
        uint2 pk;
        pk.x = (unsigned)f2bf(v.x) | ((unsigned)f2bf(v.y) << 16);
        pk.y = (unsigned)f2bf(v.z) | ((unsigned)f2bf(v.w) << 16);
        ((uint2*)xb)[i] = pk;
    }

    __shared__ double sm[256];
    sm[threadIdx.x] = local;
    __syncthreads();
    for (int s = 128; s > 0; s >>= 1) {
        if (threadIdx.x < s) sm[threadIdx.x] += sm[threadIdx.x + s];
        __syncthreads();
    }
    if (threadIdx.x == 0) atomicAdd(sum, sm[0]);
}

// ---------------- gamma only (fallback path) ----------------
__global__ __launch_bounds__(256) void k_gamma(const float* __restrict__ w,
                                               double* __restrict__ sum) {
    const int n4 = (K_DIM * N_OUT) / 4;
    int idx = blockIdx.x * blockDim.x + threadIdx.x;
    int stride = gridDim.x * blockDim.x;
    const float4* w4 = (const float4*)w;
    double local = 0.0;
    for (int i = idx; i < n4; i += stride) {
        float4 v = w4[i];
        local += (double)fabsf(v.x) + (double)fabsf(v.y) +
                 (double)fabsf(v.z) + (double)fabsf(v.w);
    }
    __shared__ double sm[256];
    sm[threadIdx.x] = local;
    __syncthreads();
    for (int s = 128; s > 0; s >>= 1) {
        if (threadIdx.x < s) sm[threadIdx.x] += sm[threadIdx.x + s];
        __syncthreads();
    }
    if (threadIdx.x == 0) atomicAdd(sum, sm[0]);
}

// ---------------- quantize W -> ternary bf16 + bin counts ----------------
__global__ __launch_bounds__(256) void k_quant(const float* __restrict__ w,
                                               const double* __restrict__ sum,
                                               unsigned short* __restrict__ wq,
                                               unsigned int* __restrict__ counts,
                                               int do_store) {
    const float gamma = (float)(*sum / NW);
    const float denom = gamma + 1e-8f;
    const int n4 = (K_DIM * N_OUT) / 4;
    int idx = blockIdx.x * blockDim.x + threadIdx.x;
    int stride = gridDim.x * blockDim.x;
    const float4* w4 = (const float4*)w;
    unsigned cm = 0, cp = 0;
    for (int i = idx; i < n4; i += stride) {
        float4 v = w4[i];
        float q0 = fminf(1.f, fmaxf(-1.f, rintf(v.x / denom)));
        float q1 = fminf(1.f, fmaxf(-1.f, rintf(v.y / denom)));
        float q2 = fminf(1.f, fmaxf(-1.f, rintf(v.z / denom)));
        float q3 = fminf(1.f, fmaxf(-1.f, rintf(v.w / denom)));
        cm += (q0 < -0.5f) + (q1 < -0.5f) + (q2 < -0.5f) + (q3 < -0.5f);
        cp += (q0 >  0.5f) + (q1 >  0.5f) + (q2 >  0.5f) + (q3 >  0.5f);
        if (do_store) {
            unsigned b0 = (q0 < -0.5f) ? 0xBF80u : (q0 > 0.5f ? 0x3F80u : 0u);
            unsigned b1 = (q1 < -0.5f) ? 0xBF80u : (q1 > 0.5f ? 0x3F80u : 0u);
            unsigned b2 = (q2 < -0.5f) ? 0xBF80u : (q2 > 0.5f ? 0x3F80u : 0u);
            unsigned b3 = (q3 < -0.5f) ? 0xBF80u : (q3 > 0.5f ? 0x3F80u : 0u);
            uint2 pk;
            pk.x = b0 | (b1 << 16);
            pk.y = b2 | (b3 << 16);
            ((uint2*)wq)[i] = pk;
        }
    }
    __shared__ unsigned smc[512];
    smc[threadIdx.x] = cm;
    smc[256 + threadIdx.x] = cp;
    __syncthreads();
    for (int s = 128; s > 0; s >>= 1) {
        if (threadIdx.x < s) {
            smc[threadIdx.x] += smc[threadIdx.x + s];
            smc[256 + threadIdx.x] += smc[256 + threadIdx.x + s];
        }
        __syncthreads();
    }
    if (threadIdx.x == 0) {
        atomicAdd(&counts[0], smc[0]);
        atomicAdd(&counts[1], smc[256]);
    }
}

// ---------------- entropy + t_current ----------------
__global__ void k_fin(const unsigned int* __restrict__ counts,
                      float* __restrict__ outs) {
    double n = NW;
    double c1 = (double)counts[0];
    double c2 = (double)counts[1];
    double c0 = n - c1 - c2;
    double H = 0.0;
    if (c1 > 0.0) { double p = c1 / n; H -= p * log2(p); }
    if (c0 > 0.0) { double p = c0 / n; H -= p * log2(p); }
    if (c2 > 0.0) { double p = c2 / n; H -= p * log2(p); }
    float Hf = (float)H;
    float heat = 100.0f * fmaxf(Hf, 0.0f);
    outs[0] = -10.0f + (50.0f + heat) * 0.5f;
    outs[1] = Hf;
}

// ===== 256x256 bf16 MFMA GEMM, 8-phase / 2-Ktile iter (R12: hoisted addr) ====
// Body/schedule identical to R11 (verified: absmax 1.0, 0 conflicts), with
// staging addresses hoisted: 4 per-thread global pointers (one per slot),
// advanced +64 elems per use; LDS dests are compile-time constants per call
// site. Removes ~20 VALU/SALU per stage from the serial pre-barrier path.
//
// Stage stream (1/phase):
//   ph0:T(o).A0  ph1:T(o).A1  ph2:T(e+2).B0  ph3:T(e+2).B1
//   ph4:T(e+2).A0 ph5:T(e+2).A1 ph6:T(o+2).B0 ph7:T(o+2).B1
// Gates: vmcnt(4) at ph3 & ph7 only (2 stage-pairs in flight; FIFO audit:
// gate waits only for stages issued >=2 phases prior). Last iter -> vmcnt(0).
// Phase body: [reads][stage][bar][lgkmcnt(0)][setprio+16 MFMA][bar].

#define MFMA_Q(ACCM, ACCN, AF, BF)                                             \
    __builtin_amdgcn_s_setprio(1);                                             \
    _Pragma("unroll") for (int mm = 0; mm < 4; ++mm)                           \
    _Pragma("unroll") for (int nn = 0; nn < 2; ++nn)                           \
    _Pragma("unroll") for (int ks = 0; ks < 2; ++ks)                           \
        acc[(ACCM) + mm][(ACCN) + nn] = __builtin_amdgcn_mfma_f32_16x16x32_bf16( \
            AF[mm][ks], BF[nn][ks], acc[(ACCM) + mm][(ACCN) + nn], 0, 0, 0);   \
    __builtin_amdgcn_s_setprio(0);

#define RD_A(PTR, BASE)                                                        \
    _Pragma("unroll") for (int mm = 0; mm < 4; ++mm)                           \
    _Pragma("unroll") for (int ks = 0; ks < 2; ++ks)                           \
        afr[mm][ks] = *(const bf16x8*)((PTR) + (ks * 8 + (BASE) + mm) * 1024);

#define RD_B(PTR, BASE, DST)                                                   \
    _Pragma("unroll") for (int nn = 0; nn < 2; ++nn)                           \
    _Pragma("unroll") for (int ks = 0; ks < 2; ++ks)                           \
        DST[nn][ks] = *(const bf16x8*)((PTR) + (ks * 8 + (BASE) + nn) * 1024);

#define BAR   __builtin_amdgcn_s_barrier()
#define LGKM0 asm volatile("s_waitcnt lgkmcnt(0)" ::: "memory")

// stage one 16KB half: 2 x gload16 from pointer, advance pointer one K-tile
#define STAGE2(P, D)  do { gload16((P), (D)); gload16((P) + 32, (char*)(D) + 8192); (P) += 64; } while (0)

__global__ __launch_bounds__(512, 2) void k_gemm2(const unsigned short* __restrict__ A,
                                                  const unsigned short* __restrict__ B,
                                                  float* __restrict__ C) {
    extern __shared__ char smem[];
    const int tid  = threadIdx.x;
    const int lane = tid & 63;
    const int wid  = tid >> 6;
    const int wr   = wid >> 2;        // 0..1  (M)
    const int wc   = wid & 3;         // 0..3  (N)
    const int fr   = lane & 15;
    const int khi  = lane >> 4;       // 0..3

    // R9 XCD/L2-locality mapping (bijective)
    const int lin = blockIdx.x;
    const int x   = lin & 7;
    const int j   = lin >> 3;
    const int tm  = ((x & 1) << 4) + (j & 15);   // 0..31
    const int tn  = ((x >> 1) << 2) + (j >> 4);  // 0..15

    // hoisted per-thread staging pointers (one per LDS slot)
    const int srow = ((tid >> 6) << 4) + (tid & 15);   // 0..127
    const int scol = ((tid >> 4) & 3) * 8;             // 0,8,16,24
    const unsigned short* pA0 = A + (size_t)(tm * 256 +       srow) * K_DIM + scol;
    const unsigned short* pA1 = A + (size_t)(tm * 256 + 128 + srow) * K_DIM + scol;
    const unsigned short* pB0 = B + (size_t)(tn * 256 +       srow) * K_DIM + scol;
    const unsigned short* pB1 = B + (size_t)(tn * 256 + 128 + srow) * K_DIM + scol;

    // LDS dests: D(buf,slot) = smem + buf*65536 + slot*16384 + tid*16
    char* const dst = smem + tid * 16;
#define DL(BUF, SLOT) (dst + ((BUF) << 16) + ((SLOT) << 14))

    f32x4 acc[8][4] = {};

    // prologue: T0.{A0,A1,B0,B1} + T1.{B0,B1}; counted gate; publish
    STAGE2(pA0, DL(0, 0));
    STAGE2(pA1, DL(0, 1));
    STAGE2(pB0, DL(0, 2));
    STAGE2(pB1, DL(0, 3));
    STAGE2(pB0, DL(1, 2));
    STAGE2(pB1, DL(1, 3));
    asm volatile("s_waitcnt vmcnt(4)" ::: "memory");
    BAR;

    bf16x8 afr[4][2], b0[2][2], b1[2][2];
    const int bsel = (wc & 1) * 4;

    const char* aE = smem + ((size_t)wr << 14) + lane * 16;
    const char* bE = smem + 32768 + ((size_t)(wc >> 1) << 14) + bsel * 1024 + lane * 16;
    const char* aO = aE + 65536;
    const char* bO = bE + 65536;

    for (int it = 0; it < 32; ++it) {
        const bool more = (it < 31);

        // ---- ph0: reads E:A(rows0-63)+B(n0) [12]; stage T(o).A0
        RD_A(aE, 0)
        RD_B(bE, 0, b0)
        STAGE2(pA0, DL(1, 0));
        BAR; LGKM0;
        MFMA_Q(0, 0, afr, b0)
        BAR;

        // ---- ph1: reads E:B(n1) [4]; stage T(o).A1
        RD_B(bE, 2, b1)
        STAGE2(pA1, DL(1, 1));
        BAR; LGKM0;
        MFMA_Q(0, 2, afr, b1)
        BAR;

        // ---- ph2: reads E:A(rows64-127) [8]; stage T(e+2).B0
        RD_A(aE, 4)
        if (more) STAGE2(pB0, DL(0, 2));
        BAR; LGKM0;
        MFMA_Q(4, 2, afr, b1)
        BAR;

        // ---- ph3: no reads; stage T(e+2).B1; MFMA; GATE
        if (more) STAGE2(pB1, DL(0, 3));
        BAR; LGKM0;
        MFMA_Q(4, 0, afr, b0)
        if (more) { asm volatile("s_waitcnt vmcnt(4)" ::: "memory"); }
        else      { asm volatile("s_waitcnt vmcnt(0)" ::: "memory"); }
        BAR;

        // ---- ph4: reads O:A(rows0-63)+B(n0) [12]; stage T(e+2).A0
        RD_A(aO, 0)
        RD_B(bO, 0, b0)
        if (more) STAGE2(pA0, DL(0, 0));
        BAR; LGKM0;
        MFMA_Q(0, 0, afr, b0)
        BAR;

        // ---- ph5: reads O:B(n1) [4]; stage T(e+2).A1
        RD_B(bO, 2, b1)
        if (more) STAGE2(pA1, DL(0, 1));
        BAR; LGKM0;
        MFMA_Q(0, 2, afr, b1)
        BAR;

        // ---- ph6: reads O:A(rows64-127) [8]; stage T(o+2).B0
        RD_A(aO, 4)
        if (more) STAGE2(pB0, DL(1, 2));
        BAR; LGKM0;
        MFMA_Q(4, 2, afr, b1)
        BAR;

        // ---- ph7: no reads; stage T(o+2).B1; MFMA; GATE
        if (more) STAGE2(pB1, DL(1, 3));
        BAR; LGKM0;
        MFMA_Q(4, 0, afr, b0)
        if (more) { asm volatile("s_waitcnt vmcnt(4)" ::: "memory"); }
        else      { asm volatile("s_waitcnt vmcnt(0)" ::: "memory"); }
        BAR;
    }
    asm volatile("s_waitcnt vmcnt(0)" ::: "memory");

    // epilogue: C/D layout col = lane&15, row = khi*4 + j
    const size_t crow = (size_t)(tm * 256 + wr * 128 + khi * 4);
    const int    ccol = tn * 256 + wc * 64 + fr;
#pragma unroll
    for (int m = 0; m < 8; ++m)
#pragma unroll
        for (int n = 0; n < 4; ++n) {
            float* cp = C + (crow + m * 16) * N_OUT + (ccol + n * 16);
#pragma unroll
            for (int jj = 0; jj < 4; ++jj)
                cp[(size_t)jj * N_OUT] = acc[m][n][jj];
        }
#undef DL
}

// ---------------- fallback fp32 GEMM (only if ws too small) ----------------
__global__ __launch_bounds__(256) void fb_gemm(const float* __restrict__ X,
                                               const float* __restrict__ W,
                                               const double* __restrict__ sum,
                                               float* __restrict__ C) {
    __shared__ float Xs[64][33];
    __shared__ float Ws[64][33];
    const float gamma = (float)(*sum / NW);
    const float denom = gamma + 1e-8f;
    const int tid = threadIdx.x;
    const int bm = blockIdx.y * 64;
    const int bn = blockIdx.x * 64;
    const int tr = tid >> 4, tc = tid & 15;
    const int lrow = tid >> 2;
    const int lcol = (tid & 3) * 8;
    float acc[4][4] = {};
    for (int k0 = 0; k0 < K_DIM; k0 += 32) {
        const float4* xs = (const float4*)(X + (size_t)(bm + lrow) * K_DIM + k0 + lcol);
        float4 v0 = xs[0], v1 = xs[1];
        Xs[lrow][lcol + 0] = v0.x; Xs[lrow][lcol + 1] = v0.y;
        Xs[lrow][lcol + 2] = v0.z; Xs[lrow][lcol + 3] = v0.w;
        Xs[lrow][lcol + 4] = v1.x; Xs[lrow][lcol + 5] = v1.y;
        Xs[lrow][lcol + 6] = v1.z; Xs[lrow][lcol + 7] = v1.w;
        const float4* wsrc = (const float4*)(W + (size_t)(bn + lrow) * K_DIM + k0 + lcol);
        float4 w0 = wsrc[0], w1 = wsrc[1];
        Ws[lrow][lcol + 0] = fminf(1.f, fmaxf(-1.f, rintf(w0.x / denom)));
        Ws[lrow][lcol + 1] = fminf(1.f, fmaxf(-1.f, rintf(w0.y / denom)));
        Ws[lrow][lcol + 2] = fminf(1.f, fmaxf(-1.f, rintf(w0.z / denom)));
        Ws[lrow][lcol + 3] = fminf(1.f, fmaxf(-1.f, rintf(w0.w / denom)));
        Ws[lrow][lcol + 4] = fminf(1.f, fmaxf(-1.f, rintf(w1.x / denom)));
        Ws[lrow][lcol + 5] = fminf(1.f, fmaxf(-1.f, rintf(w1.y / denom)));
        Ws[lrow][lcol + 6] = fminf(1.f, fmaxf(-1.f, rintf(w1.z / denom)));
        Ws[lrow][lcol + 7] = fminf(1.f, fmaxf(-1.f, rintf(w1.w / denom)));
        __syncthreads();
#pragma unroll 8
        for (int kk = 0; kk < 32; ++kk) {
            float a0 = Xs[tr * 4 + 0][kk], a1 = Xs[tr * 4 + 1][kk];
            float a2 = Xs[tr * 4 + 2][kk], a3 = Xs[tr * 4 + 3][kk];
            float b0 = Ws[tc * 4 + 0][kk], b1 = Ws[tc * 4 + 1][kk];
            float b2 = Ws[tc * 4 + 2][kk], b3 = Ws[tc * 4 + 3][kk];
            acc[0][0] += a0 * b0; acc[0][1] += a0 * b1; acc[0][2] += a0 * b2; acc[0][3] += a0 * b3;
            acc[1][0] += a1 * b0; acc[1][1] += a1 * b1; acc[1][2] += a1 * b2; acc[1][3] += a1 * b3;
            acc[2][0] += a2 * b0; acc[2][1] += a2 * b1; acc[2][2] += a2 * b2; acc[2][3] += a2 * b3;
            acc[3][0] += a3 * b0; acc[3][1] += a3 * b1; acc[3][2] += a3 * b2; acc[3][3] += a3 * b3;
        }
        __syncthreads();
    }
#pragma unroll
    for (int i = 0; i < 4; ++i)
#pragma unroll
        for (int jj = 0; jj < 4; ++jj)
            C[(size_t)(bm + tr * 4 + i) * N_OUT + (bn + tc * 4 + jj)] = acc[i][jj];
}

extern "C" void kernel_launch(void* const* d_in, const int* in_sizes, int n_in,
                              void* d_out, int out_size, void* d_ws, size_t ws_size,
                              hipStream_t stream) {
    (void)in_sizes; (void)n_in; (void)out_size;
    const float* x = (const float*)d_in[0];
    const float* w = (const float*)d_in[1];
    float* out = (float*)d_out;
    float* scalars = out + (size_t)M_ROWS * N_OUT;   // [t_current, entropy]

    double* sum = (double*)d_ws;
    unsigned int* counts = (unsigned int*)((char*)d_ws + 8);
    unsigned short* xb = (unsigned short*)((char*)d_ws + 64);
    unsigned short* wq = (unsigned short*)((char*)d_ws + 64 + (size_t)M_ROWS * K_DIM * 2);

    const size_t need = 64 + (size_t)M_ROWS * K_DIM * 2 + (size_t)N_OUT * K_DIM * 2;
    const int fast = (ws_size >= need);

    hipMemsetAsync(d_ws, 0, 16, stream);

    if (fast) {
        k_gamma_cvt<<<2048, 256, 0, stream>>>(w, x, xb, sum);
        k_quant<<<1024, 256, 0, stream>>>(w, sum, wq, counts, 1);
        k_fin<<<1, 1, 0, stream>>>(counts, scalars);
        hipFuncSetAttribute(reinterpret_cast<const void*>(k_gemm2),
                            hipFuncAttributeMaxDynamicSharedMemorySize, 131072);
        k_gemm2<<<dim3(512), 512, 131072, stream>>>(xb, wq, out);
    } else {
        k_gamma<<<1024, 256, 0, stream>>>(w, sum);
        k_quant<<<1024, 256, 0, stream>>>(w, sum, nullptr, counts, 0);
        k_fin<<<1, 1, 0, stream>>>(counts, scalars);
        dim3 grid(N_OUT / 64, M_ROWS / 64);
        fb_gemm<<<grid, 256, 0, stream>>>(x, w, sum, out);
    }
}